// Round 9
// baseline (1209.179 us; speedup 1.0000x reference)
//
#include <hip/hip_runtime.h>
#include <math.h>

#define NB 16
#define INW 256
#define GN 100
#define NV (GN*GN)          // 10000
#define NPROB (NB*2)        // 32
#define K_TOP 20
#define HSZ 8192
#define HMASK (HSZ-1)
#define EMPTYK 0xFFFFFFFFu
#define KB 64               // rank buckets per problem
#define SNAPN 8             // snapshots (every 8 buckets)
#define RCAP 3072           // max regions per problem
#define MYCAP 128           // max edges per bucket (= ceil(HSZ/KB))
#define LISTCAP 3072        // max bars per problem (bars <= R-1)

// ws byte offsets (end 6,589,952 B — under proven 6.87 MB budget)
#define OFF_RES   0               // NB*NV f32 = 640000
#define OFF_LAB   640000          // NPROB*NV u16
#define OFF_DENSE 1280000         // NPROB*NV u16
#define OFF_ROOTV 1920000         // NPROB*RCAP u16 = 196608
#define OFF_D2B   2116608         // NPROB*RCAP f32 = 393216
#define OFF_EDGES 2509824         // NPROB*HSZ u64 = 2097152
#define OFF_RORD  OFF_EDGES       // overlay: NPROB*RCAP u64 (dead before hash_k writes edges)
#define OFF_STATE 4606976         // SNAPN*RCAP u16 per problem = 1572864 total
#define OFF_ECNT  6179840         // NPROB u32
#define OFF_RCNT  6179968         // NPROB u32
#define OFF_QUANT 6180096         // NPROB*KB u64 = 16384
#define OFF_LCNT  6196480         // NPROB u32
#define OFF_LIST  6196608         // NPROB*LISTCAP f32 = 393216
#define OFF_PART  6589824         // NPROB f32

__device__ __forceinline__ int imin(int a, int b){ return a < b ? a : b; }
__device__ __forceinline__ int imax(int a, int b){ return a > b ? a : b; }

__device__ __forceinline__ unsigned mono32(float f){
  unsigned b = __float_as_uint(f);
  return (b & 0x80000000u) ? ~b : (b | 0x80000000u);
}
__device__ __forceinline__ float unmono(unsigned m){
  unsigned b = (m & 0x80000000u) ? (m ^ 0x80000000u) : ~m;
  return __uint_as_float(b);
}

// path-halving find (concurrent-safe: all writes point to ancestors)
__device__ __forceinline__ unsigned uf_find(volatile unsigned* par, unsigned x){
  unsigned p = par[x];
  while (p != x) {
    unsigned g = par[p];
    if (g != p) par[x] = g;
    x = g;
    p = par[x];
  }
  return x;
}
// lock-free min-hook union (ECL-CC style); min dense id root == elder
__device__ __forceinline__ void uf_union(volatile unsigned* vpar, unsigned* par,
                                         unsigned a, unsigned b){
  while (1) {
    unsigned ra = uf_find(vpar, a);
    unsigned rb = uf_find(vpar, b);
    if (ra == rb) break;
    unsigned lo = (ra < rb) ? ra : rb, hi = (ra < rb) ? rb : ra;
    if (atomicCAS(&par[hi], hi, lo) == hi) break;
    a = lo; b = hi;
  }
}

// keys-cubic a=-0.5 weights (renormalized over valid taps)
__device__ __forceinline__ void cub_w(int i, int& j0, float w[4]) {
  double inv = (double)INW / (double)GN;
  double sf  = ((double)i + 0.5) * inv - 0.5;
  j0 = (int)floor(sf) - 1;
  double wd[4]; double s = 0.0;
  #pragma unroll
  for (int k = 0; k < 4; ++k) {
    int j = j0 + k;
    double t = fabs(sf - (double)j);
    double v;
    if (t < 1.0)      v = ((1.5*t - 2.5)*t)*t + 1.0;
    else if (t < 2.0) v = ((-0.5*t + 2.5)*t - 4.0)*t + 2.0;
    else              v = 0.0;
    if (j < 0 || j >= INW) v = 0.0;
    wd[k] = v; s += v;
  }
  #pragma unroll
  for (int k = 0; k < 4; ++k) w[k] = (float)(wd[k] / s);
}

// ---------------------------------------------------------------------------
// Kernel 1: separable bicubic resize 256x256 -> 100x100
// ---------------------------------------------------------------------------
__global__ __launch_bounds__(256) void resize_k(const float* __restrict__ in, float* ws) {
  float* outp = (float*)((char*)ws + OFF_RES);
  int idx = blockIdx.x * 256 + threadIdx.x;
  if (idx >= NB * NV) return;
  int b = idx / NV; int rem = idx - b * NV;
  int i = rem / GN; int j = rem - i * GN;
  const float* img = in + (size_t)b * INW * INW;
  int r0, c0; float wr[4], wc[4];
  cub_w(i, r0, wr);
  cub_w(j, c0, wc);
  float acc = 0.f;
  #pragma unroll
  for (int kr = 0; kr < 4; ++kr) {
    int rr = imin(imax(r0 + kr, 0), INW - 1);
    const float* row = img + rr * INW;
    int c0c = imin(imax(c0 + 0, 0), INW - 1);
    int c1c = imin(imax(c0 + 1, 0), INW - 1);
    int c2c = imin(imax(c0 + 2, 0), INW - 1);
    int c3c = imin(imax(c0 + 3, 0), INW - 1);
    float rs = wc[0]*row[c0c] + wc[1]*row[c1c] + wc[2]*row[c2c] + wc[3]*row[c3c];
    acc += wr[kr] * rs;
  }
  outp[idx] = acc;
}

// ---------------------------------------------------------------------------
// Kernel 2: watershed labels + root compaction
// ---------------------------------------------------------------------------
__global__ __launch_bounds__(256) void label_k(float* ws) {
  __shared__ unsigned sm[NV];
  __shared__ unsigned short lab[NV];
  __shared__ unsigned cnt[256];
  int p = blockIdx.x, samp = p >> 1, neg = p & 1, tid = threadIdx.x;
  const float* res = (const float*)((const char*)ws + OFF_RES) + samp * NV;
  unsigned short* glab = (unsigned short*)((char*)ws + OFF_LAB) + (size_t)p * NV;
  unsigned short* rootv = (unsigned short*)((char*)ws + OFF_ROOTV) + (size_t)p * RCAP;
  unsigned long long* rord = (unsigned long long*)((char*)ws + OFF_RORD) + (size_t)p * RCAP;
  unsigned* rcnt = (unsigned*)((char*)ws + OFF_RCNT);
  float sgn = neg ? -1.f : 1.f;
  for (int i = tid; i < NV; i += 256) sm[i] = mono32(sgn * res[i]);
  __syncthreads();
  const int nd = neg ? 4 : 6;
  for (int v = tid; v < NV; v += 256) {
    int r = v / GN, c = v - r * GN;
    unsigned long long best = ((unsigned long long)sm[v] << 32) | (unsigned)~(unsigned)v;
    unsigned bi = (unsigned)v;
    bool cb[6] = { c < GN-1, c > 0, r < GN-1, r > 0,
                   (r < GN-1) && (c < GN-1), (r > 0) && (c > 0) };
    int  off[6] = { 1, -1, GN, -GN, GN+1, -(GN+1) };
    #pragma unroll
    for (int d = 0; d < 6; ++d) {
      if (d < nd && cb[d]) {
        unsigned y = (unsigned)(v + off[d]);
        unsigned long long o = ((unsigned long long)sm[y] << 32) | (unsigned)~y;
        if (o > best) { best = o; bi = y; }
      }
    }
    lab[v] = (unsigned short)bi;
  }
  __syncthreads();
  for (int v = tid; v < NV; v += 256) {
    unsigned r = lab[v];
    while (1) { unsigned n = lab[r]; if (n == r) break; r = n; }
    lab[v] = (unsigned short)r;
    glab[v] = (unsigned short)r;
  }
  __syncthreads();
  unsigned my = 0;
  for (int v = tid; v < NV; v += 256) if (lab[v] == (unsigned short)v) ++my;
  cnt[tid] = my;
  __syncthreads();
  for (int off = 1; off < 256; off <<= 1) {
    unsigned t = (tid >= off) ? cnt[tid - off] : 0u;
    __syncthreads();
    cnt[tid] += t;
    __syncthreads();
  }
  unsigned base = cnt[tid] - my;
  for (int v = tid; v < NV; v += 256) {
    if (lab[v] == (unsigned short)v) {
      if (base < RCAP) {
        rootv[base] = (unsigned short)v;
        rord[base] = ((unsigned long long)sm[v] << 32) | (unsigned)~(unsigned)v;
      }
      ++base;
    }
  }
  if (tid == 255) rcnt[p] = (cnt[255] > RCAP) ? RCAP : cnt[255];
}

// ---------------------------------------------------------------------------
// Kernel 3: rank roots desc (elder order) -> dense ids + birth table
// ---------------------------------------------------------------------------
__global__ __launch_bounds__(256) void rank_root_k(float* ws) {
  __shared__ unsigned long long ro[RCAP];     // 24KB
  int p = blockIdx.x / 4, sl = blockIdx.x % 4, tid = threadIdx.x;
  const unsigned short* rootv = (const unsigned short*)((const char*)ws + OFF_ROOTV) + (size_t)p * RCAP;
  const unsigned long long* rord = (const unsigned long long*)((const char*)ws + OFF_RORD) + (size_t)p * RCAP;
  unsigned short* dense = (unsigned short*)((char*)ws + OFF_DENSE) + (size_t)p * NV;
  float* d2b = (float*)((char*)ws + OFF_D2B) + (size_t)p * RCAP;
  const unsigned* rcnt = (const unsigned*)((const char*)ws + OFF_RCNT);
  unsigned R = rcnt[p];
  for (unsigned i = tid; i < R; i += 256) ro[i] = rord[i];
  __syncthreads();
  unsigned RS = (R + 3) / 4;
  unsigned lo = sl * RS, hi = lo + RS; if (hi > R) hi = R;
  for (unsigned i = lo + tid; i < hi; i += 256) {
    unsigned long long oi = ro[i];
    unsigned r = 0;
    for (unsigned j = 0; j < R; ++j) r += (ro[j] > oi) ? 1u : 0u;
    dense[rootv[i]] = (unsigned short)r;
    d2b[r] = unmono((unsigned)(oi >> 32));
  }
}

// ---------------------------------------------------------------------------
// Kernel 4: boundary-edge hashing (dense pids, u32 events) + compaction
// ---------------------------------------------------------------------------
__global__ __launch_bounds__(256) void hash_k(float* ws) {
  __shared__ unsigned sm[NV];
  __shared__ unsigned hkey[HSZ];
  __shared__ unsigned hval[HSZ];
  __shared__ unsigned short dlab[NV];
  __shared__ unsigned cnt[256];
  int p = blockIdx.x, samp = p >> 1, neg = p & 1, tid = threadIdx.x;
  const float* res = (const float*)((const char*)ws + OFF_RES) + samp * NV;
  const unsigned short* glab = (const unsigned short*)((const char*)ws + OFF_LAB) + (size_t)p * NV;
  const unsigned short* gdense = (const unsigned short*)((const char*)ws + OFF_DENSE) + (size_t)p * NV;
  unsigned long long* gedges = (unsigned long long*)((char*)ws + OFF_EDGES) + (size_t)p * HSZ;
  unsigned* ecnt = (unsigned*)((char*)ws + OFF_ECNT);
  unsigned* lcnt = (unsigned*)((char*)ws + OFF_LCNT);
  unsigned long long* quant = (unsigned long long*)((char*)ws + OFF_QUANT) + p * KB;
  float sgn = neg ? -1.f : 1.f;
  for (int i = tid; i < NV; i += 256) {
    sm[i] = mono32(sgn * res[i]);
    dlab[i] = gdense[glab[i]];
  }
  for (int s = tid; s < HSZ; s += 256) { hkey[s] = EMPTYK; hval[s] = 0u; }
  if (tid == 0) lcnt[p] = 0u;
  if (tid < KB) quant[tid] = (tid == 0) ? ~0ull : 0ull;
  __syncthreads();
  for (int v = tid; v < NV; v += 256) {
    int r = v / GN, c = v - r * GN;
    unsigned a = dlab[v];
    unsigned sv = sm[v];
    bool vb[3] = { c < GN-1, r < GN-1, (!neg) && (r < GN-1) && (c < GN-1) };
    int  vo[3] = { 1, GN, GN+1 };
    #pragma unroll
    for (int d = 0; d < 3; ++d) {
      if (vb[d]) {
        unsigned w = (unsigned)(v + vo[d]);
        unsigned b = dlab[w];
        if (a != b) {
          unsigned sw = sm[w];
          unsigned ev = (sv < sw) ? sv : sw;
          unsigned dlo = (a < b) ? a : b, dhi = (a < b) ? b : a;
          unsigned pid = (dlo << 16) | dhi;
          unsigned h = (pid * 2654435761u) >> 19;
          for (int pr2 = 0; pr2 < HSZ; ++pr2) {
            unsigned k = hkey[h];
            if (k == EMPTYK) {
              unsigned old = atomicCAS(&hkey[h], EMPTYK, pid);
              k = (old == EMPTYK) ? pid : old;
            }
            if (k == pid) { atomicMax(&hval[h], ev); break; }
            h = (h + 1) & HMASK;
          }
        }
      }
    }
  }
  __syncthreads();
  unsigned my = 0;
  for (int s = tid; s < HSZ; s += 256) if (hkey[s] != EMPTYK) ++my;
  cnt[tid] = my;
  __syncthreads();
  for (int off = 1; off < 256; off <<= 1) {
    unsigned t = (tid >= off) ? cnt[tid - off] : 0u;
    __syncthreads();
    cnt[tid] += t;
    __syncthreads();
  }
  unsigned base = cnt[tid] - my;
  for (int s = tid; s < HSZ; s += 256) {
    if (hkey[s] != EMPTYK) {
      gedges[base++] = ((unsigned long long)hval[s] << 32) | hkey[s];
    }
  }
  if (tid == 255) ecnt[p] = cnt[255];
}

// ---------------------------------------------------------------------------
// Kernel 5: exact rank-quantile splitters, scalar-broadcast scan (no LDS
// mirror). One thread per edge; inner loop address is wave-uniform.
// ---------------------------------------------------------------------------
__global__ __launch_bounds__(256) void quantile_k(float* ws) {
  int p = blockIdx.x / 32, sl = blockIdx.x % 32, tid = threadIdx.x;
  const unsigned long long* gedges = (const unsigned long long*)((const char*)ws + OFF_EDGES) + (size_t)p * HSZ;
  const unsigned* ecnt = (const unsigned*)((const char*)ws + OFF_ECNT);
  unsigned long long* quant = (unsigned long long*)((char*)ws + OFF_QUANT) + p * KB;
  unsigned E = ecnt[p]; if (E > HSZ) E = HSZ;
  unsigned chunk = (E + KB - 1) / KB;
  unsigned idx = sl * 256 + tid;
  if (idx >= E) return;
  unsigned long long x = gedges[idx];
  unsigned r = 0;
  for (unsigned j = 0; j < E; ++j) {
    unsigned long long y = gedges[j];     // uniform address -> scalar load
    r += (y > x) ? 1u : 0u;
  }
  if (r >= chunk && (r % chunk) == 0) {
    unsigned m = r / chunk;
    if (m < KB) quant[m] = x;
  }
}

// ---------------------------------------------------------------------------
// Kernel 6: shared prefix CC states. One block per problem; sequential over
// 8 snapshot epochs: snapshot compressed par, then union next 8 buckets.
// Snapshot s = CC of all edges > quant[8s]  (prefix of buckets < 8s).
// ---------------------------------------------------------------------------
__global__ __launch_bounds__(256) void prefix_cc_k(float* ws) {
  __shared__ unsigned par[RCAP];              // 12KB
  int p = blockIdx.x, tid = threadIdx.x;
  const unsigned long long* gedges = (const unsigned long long*)((const char*)ws + OFF_EDGES) + (size_t)p * HSZ;
  const unsigned long long* quant = (const unsigned long long*)((const char*)ws + OFF_QUANT) + p * KB;
  unsigned short* state = (unsigned short*)((char*)ws + OFF_STATE) + (size_t)p * SNAPN * RCAP;
  const unsigned* ecnt = (const unsigned*)((const char*)ws + OFF_ECNT);
  const unsigned* rcnt = (const unsigned*)((const char*)ws + OFF_RCNT);
  unsigned E = ecnt[p]; if (E > HSZ) E = HSZ;
  unsigned R = rcnt[p]; if (R > RCAP) R = RCAP;
  for (unsigned d = tid; d < R; d += 256) par[d] = d;
  __syncthreads();
  volatile unsigned* vpar = par;
  for (int s = 0; s < SNAPN; ++s) {
    // compress + snapshot
    for (unsigned d = tid; d < R; d += 256) {
      unsigned r = d;
      while (vpar[r] != r) r = vpar[r];
      par[d] = r;
      state[s * RCAP + d] = (unsigned short)r;
    }
    __syncthreads();
    // union buckets 8s .. 8s+7:  quant[8s+8] < it <= quant[8s]
    unsigned long long qhi = quant[8 * s];
    unsigned long long qlo = (s == SNAPN - 1) ? 0ull : quant[8 * s + 8];
    for (unsigned e = tid; e < E; e += 256) {
      unsigned long long it = gedges[e];
      if (it <= qhi && it > qlo) {
        unsigned pid = (unsigned)it;
        uf_union(vpar, par, pid >> 16, pid & 0xffffu);
      }
    }
    __syncthreads();
  }
}

// ---------------------------------------------------------------------------
// Kernel 7: bucketed elder-rule Kruskal. One block per (problem, bucket).
// Load snapshot bk>>3, replay <=7*128 residual prefix edges (CAS hooks),
// rank-sort own <=128 edges, serial Kruskal on lane 0.
// ---------------------------------------------------------------------------
__global__ __launch_bounds__(256) void kruskal_bucket_k(float* ws) {
  __shared__ unsigned par[RCAP];                // 12KB
  __shared__ float birth[RCAP];                 // 12KB
  __shared__ unsigned long long my[MYCAP];      // 1KB
  __shared__ unsigned long long my2[MYCAP + 1]; // 1KB
  __shared__ unsigned mycnt;
  int p = blockIdx.x / KB, bk = blockIdx.x % KB, tid = threadIdx.x;
  const unsigned long long* gedges = (const unsigned long long*)((const char*)ws + OFF_EDGES) + (size_t)p * HSZ;
  const float* d2b = (const float*)((const char*)ws + OFF_D2B) + (size_t)p * RCAP;
  const unsigned short* state = (const unsigned short*)((const char*)ws + OFF_STATE) + (size_t)p * SNAPN * RCAP + (size_t)(bk >> 3) * RCAP;
  const unsigned* ecnt = (const unsigned*)((const char*)ws + OFF_ECNT);
  const unsigned* rcnt = (const unsigned*)((const char*)ws + OFF_RCNT);
  const unsigned long long* quant = (const unsigned long long*)((const char*)ws + OFF_QUANT) + p * KB;
  unsigned* lcnt = (unsigned*)((char*)ws + OFF_LCNT);
  float* glist = (float*)((char*)ws + OFF_LIST) + (size_t)p * LISTCAP;
  unsigned E = ecnt[p]; if (E > HSZ) E = HSZ;
  unsigned R = rcnt[p]; if (R > RCAP) R = RCAP;
  unsigned long long qrep = quant[bk & ~7];   // snapshot boundary
  unsigned long long qup  = quant[bk];
  unsigned long long qdn  = (bk == KB - 1) ? 0ull : quant[bk + 1];
  if (tid == 0) mycnt = 0;
  for (unsigned d = tid; d < R; d += 256) { par[d] = state[d]; birth[d] = d2b[d]; }
  __syncthreads();
  volatile unsigned* vpar = par;
  // one stream: replay residual prefix + gather own edges
  for (unsigned e = tid; e < E; e += 256) {
    unsigned long long it = gedges[e];
    if (it > qup) {
      if (it <= qrep) {
        unsigned pid = (unsigned)it;
        uf_union(vpar, par, pid >> 16, pid & 0xffffu);
      }
    } else if (it > qdn) {
      unsigned k = atomicAdd(&mycnt, 1u);
      if (k < MYCAP) my[k] = it;
    }
  }
  __syncthreads();
  // compression sweep
  for (unsigned d = tid; d < R; d += 256) {
    unsigned r = d;
    while (vpar[r] != r) r = vpar[r];
    par[d] = r;
  }
  unsigned mc = mycnt; if (mc > MYCAP) mc = MYCAP;
  if (tid == 0) my2[mc] = 0ull;
  // local rank sort desc (items unique)
  for (unsigned i = tid; i < mc; i += 256) {
    unsigned long long x = my[i];
    unsigned r = 0;
    for (unsigned j = 0; j < mc; ++j) r += (my[j] > x) ? 1u : 0u;
    my2[r] = x;
  }
  __syncthreads();
  // serial Kruskal; winner = min dense id (elder by construction)
  if (tid != 0) return;
  unsigned long long it = my2[0];
  for (unsigned e = 0; e < mc; ++e) {
    unsigned long long nx = my2[e + 1];
    unsigned ev = (unsigned)(it >> 32);
    unsigned pid = (unsigned)it;
    unsigned ca = pid >> 16, cb = pid & 0xffffu;
    while (1) {
      unsigned pa = par[ca], pb = par[cb];
      bool da = (pa == ca), db = (pb == cb);
      if (da && db) break;
      unsigned ga = par[pa], gb = par[pb];
      if (!da) { par[ca] = ga; ca = ga; }
      if (!db) { par[cb] = gb; cb = gb; }
    }
    if (ca != cb) {
      unsigned win = (ca < cb) ? ca : cb;
      unsigned los = (ca < cb) ? cb : ca;
      float bar = birth[los] - unmono(ev);
      unsigned idx = atomicAdd(&lcnt[p], 1u);
      if (idx < LISTCAP) glist[idx] = bar;
      par[los] = win;
    }
    it = nx;
  }
}

// ---------------------------------------------------------------------------
// Kernel 8: per-problem top-20 over compact bar list -> partial[p]
// ---------------------------------------------------------------------------
__global__ __launch_bounds__(256) void topk_k(float* ws) {
  __shared__ float sl[LISTCAP];
  __shared__ float rv[256];
  __shared__ int   ri[256];
  int p = blockIdx.x, tid = threadIdx.x;
  const float* glist = (const float*)((const char*)ws + OFF_LIST) + (size_t)p * LISTCAP;
  const unsigned* lcnt = (const unsigned*)((const char*)ws + OFF_LCNT);
  float* part = (float*)((char*)ws + OFF_PART);
  unsigned cnt = lcnt[p]; if (cnt > LISTCAP) cnt = LISTCAP;
  for (unsigned i = tid; i < cnt; i += 256) sl[i] = glist[i];
  __syncthreads();
  float acc = 0.f;
  for (int k = 0; k < K_TOP; ++k) {
    float mv = -1.f; int mi = LISTCAP;
    for (unsigned i = tid; i < cnt; i += 256) {
      float v = sl[i];
      if (v > mv) { mv = v; mi = (int)i; }
    }
    rv[tid] = mv; ri[tid] = mi;
    __syncthreads();
    for (int s = 128; s > 0; s >>= 1) {
      if (tid < s) {
        if (rv[tid+s] > rv[tid] || (rv[tid+s] == rv[tid] && ri[tid+s] < ri[tid])) {
          rv[tid] = rv[tid+s]; ri[tid] = ri[tid+s];
        }
      }
      __syncthreads();
    }
    if (tid == 0) {
      float best = rv[0] > 0.f ? rv[0] : 0.f;
      float sgnk = (k < 5) ? -1.f : 1.f;
      acc += sgnk * best * best;
      if (ri[0] < LISTCAP) sl[ri[0]] = -2.f;
    }
    __syncthreads();
  }
  if (tid == 0) part[p] = acc;
}

// ---------------------------------------------------------------------------
// Kernel 9: deterministic final reduction (mean over batch)
// ---------------------------------------------------------------------------
__global__ void final_k(float* ws, float* out) {
  if (threadIdx.x == 0 && blockIdx.x == 0) {
    const float* part = (const float*)((const char*)ws + OFF_PART);
    float s = 0.f;
    for (int i = 0; i < NPROB; ++i) s += part[i];
    out[0] = s / (float)NB;
  }
}

extern "C" void kernel_launch(void* const* d_in, const int* in_sizes, int n_in,
                              void* d_out, int out_size, void* d_ws, size_t ws_size,
                              hipStream_t stream) {
  const float* in = (const float*)d_in[0];
  float* ws = (float*)d_ws;
  float* out = (float*)d_out;
  hipLaunchKernelGGL(resize_k, dim3((NB * NV + 255) / 256), dim3(256), 0, stream, in, ws);
  hipLaunchKernelGGL(label_k, dim3(NPROB), dim3(256), 0, stream, ws);
  hipLaunchKernelGGL(rank_root_k, dim3(NPROB * 4), dim3(256), 0, stream, ws);
  hipLaunchKernelGGL(hash_k, dim3(NPROB), dim3(256), 0, stream, ws);
  hipLaunchKernelGGL(quantile_k, dim3(NPROB * 32), dim3(256), 0, stream, ws);
  hipLaunchKernelGGL(prefix_cc_k, dim3(NPROB), dim3(256), 0, stream, ws);
  hipLaunchKernelGGL(kruskal_bucket_k, dim3(NPROB * KB), dim3(256), 0, stream, ws);
  hipLaunchKernelGGL(topk_k, dim3(NPROB), dim3(256), 0, stream, ws);
  hipLaunchKernelGGL(final_k, dim3(1), dim3(64), 0, stream, ws, out);
}

// Round 10
// 758.931 us; speedup vs baseline: 1.5933x; 1.5933x over previous
//
#include <hip/hip_runtime.h>
#include <math.h>

#define NB 16
#define INW 256
#define GN 100
#define NV (GN*GN)          // 10000
#define NPROB (NB*2)        // 32
#define K_TOP 20
#define HSZ 8192
#define HMASK (HSZ-1)
#define EMPTYK 0xFFFFFFFFu
#define KB 32               // positional buckets per problem
#define SNAPN 4             // snapshots (every 8 buckets)
#define RCAP 3072           // max regions per problem
#define MYCAP 256           // max edges per bucket (= ceil(HSZ/KB))
#define LISTCAP 3072        // max bars per problem (bars <= R-1)

// ws byte offsets (end 5,787,264 B — well under proven budget)
#define OFF_RES   0               // NB*NV f32 = 640000
#define OFF_LAB   640000          // NPROB*NV u16
#define OFF_DENSE 1280000         // NPROB*NV u16
#define OFF_ROOTV 1920000         // NPROB*RCAP u16 = 196608
#define OFF_D2B   2116608         // NPROB*RCAP f32 = 393216
#define OFF_EDGES 2509824         // NPROB*HSZ u64 = 2097152
#define OFF_RORD  OFF_EDGES       // overlay: rord dead before hash_k writes edges
#define OFF_STATE 4606976         // NPROB*SNAPN*RCAP u16 = 786432
#define OFF_ECNT  5393408         // NPROB u32
#define OFF_RCNT  5393536         // NPROB u32
#define OFF_LCNT  5393664         // NPROB u32
#define OFF_LIST  5393792         // NPROB*LISTCAP f32 = 393216
#define OFF_PART  5787008         // NPROB f32

__device__ __forceinline__ int imin(int a, int b){ return a < b ? a : b; }
__device__ __forceinline__ int imax(int a, int b){ return a > b ? a : b; }

__device__ __forceinline__ unsigned mono32(float f){
  unsigned b = __float_as_uint(f);
  return (b & 0x80000000u) ? ~b : (b | 0x80000000u);
}
__device__ __forceinline__ float unmono(unsigned m){
  unsigned b = (m & 0x80000000u) ? (m ^ 0x80000000u) : ~m;
  return __uint_as_float(m ? b : b);
}

// path-halving find (concurrent-safe: all writes point to ancestors)
__device__ __forceinline__ unsigned uf_find(volatile unsigned* par, unsigned x){
  unsigned p = par[x];
  while (p != x) {
    unsigned g = par[p];
    if (g != p) par[x] = g;
    x = g;
    p = par[x];
  }
  return x;
}
// lock-free min-hook union; min dense id root == elder
__device__ __forceinline__ void uf_union(volatile unsigned* vpar, unsigned* par,
                                         unsigned a, unsigned b){
  while (1) {
    unsigned ra = uf_find(vpar, a);
    unsigned rb = uf_find(vpar, b);
    if (ra == rb) break;
    unsigned lo = (ra < rb) ? ra : rb, hi = (ra < rb) ? rb : ra;
    if (atomicCAS(&par[hi], hi, lo) == hi) break;
    a = lo; b = hi;
  }
}

// keys-cubic a=-0.5 weights (renormalized over valid taps)
__device__ __forceinline__ void cub_w(int i, int& j0, float w[4]) {
  double inv = (double)INW / (double)GN;
  double sf  = ((double)i + 0.5) * inv - 0.5;
  j0 = (int)floor(sf) - 1;
  double wd[4]; double s = 0.0;
  #pragma unroll
  for (int k = 0; k < 4; ++k) {
    int j = j0 + k;
    double t = fabs(sf - (double)j);
    double v;
    if (t < 1.0)      v = ((1.5*t - 2.5)*t)*t + 1.0;
    else if (t < 2.0) v = ((-0.5*t + 2.5)*t - 4.0)*t + 2.0;
    else              v = 0.0;
    if (j < 0 || j >= INW) v = 0.0;
    wd[k] = v; s += v;
  }
  #pragma unroll
  for (int k = 0; k < 4; ++k) w[k] = (float)(wd[k] / s);
}

// ---------------------------------------------------------------------------
// Kernel 1: separable bicubic resize 256x256 -> 100x100
// ---------------------------------------------------------------------------
__global__ __launch_bounds__(256) void resize_k(const float* __restrict__ in, float* ws) {
  float* outp = (float*)((char*)ws + OFF_RES);
  int idx = blockIdx.x * 256 + threadIdx.x;
  if (idx >= NB * NV) return;
  int b = idx / NV; int rem = idx - b * NV;
  int i = rem / GN; int j = rem - i * GN;
  const float* img = in + (size_t)b * INW * INW;
  int r0, c0; float wr[4], wc[4];
  cub_w(i, r0, wr);
  cub_w(j, c0, wc);
  float acc = 0.f;
  #pragma unroll
  for (int kr = 0; kr < 4; ++kr) {
    int rr = imin(imax(r0 + kr, 0), INW - 1);
    const float* row = img + rr * INW;
    int c0c = imin(imax(c0 + 0, 0), INW - 1);
    int c1c = imin(imax(c0 + 1, 0), INW - 1);
    int c2c = imin(imax(c0 + 2, 0), INW - 1);
    int c3c = imin(imax(c0 + 3, 0), INW - 1);
    float rs = wc[0]*row[c0c] + wc[1]*row[c1c] + wc[2]*row[c2c] + wc[3]*row[c3c];
    acc += wr[kr] * rs;
  }
  outp[idx] = acc;
}

// ---------------------------------------------------------------------------
// Kernel 2: watershed labels + root compaction
// ---------------------------------------------------------------------------
__global__ __launch_bounds__(256) void label_k(float* ws) {
  __shared__ unsigned sm[NV];
  __shared__ unsigned short lab[NV];
  __shared__ unsigned cnt[256];
  int p = blockIdx.x, samp = p >> 1, neg = p & 1, tid = threadIdx.x;
  const float* res = (const float*)((const char*)ws + OFF_RES) + samp * NV;
  unsigned short* glab = (unsigned short*)((char*)ws + OFF_LAB) + (size_t)p * NV;
  unsigned short* rootv = (unsigned short*)((char*)ws + OFF_ROOTV) + (size_t)p * RCAP;
  unsigned long long* rord = (unsigned long long*)((char*)ws + OFF_RORD) + (size_t)p * RCAP;
  unsigned* rcnt = (unsigned*)((char*)ws + OFF_RCNT);
  float sgn = neg ? -1.f : 1.f;
  for (int i = tid; i < NV; i += 256) sm[i] = mono32(sgn * res[i]);
  __syncthreads();
  const int nd = neg ? 4 : 6;
  for (int v = tid; v < NV; v += 256) {
    int r = v / GN, c = v - r * GN;
    unsigned long long best = ((unsigned long long)sm[v] << 32) | (unsigned)~(unsigned)v;
    unsigned bi = (unsigned)v;
    bool cb[6] = { c < GN-1, c > 0, r < GN-1, r > 0,
                   (r < GN-1) && (c < GN-1), (r > 0) && (c > 0) };
    int  off[6] = { 1, -1, GN, -GN, GN+1, -(GN+1) };
    #pragma unroll
    for (int d = 0; d < 6; ++d) {
      if (d < nd && cb[d]) {
        unsigned y = (unsigned)(v + off[d]);
        unsigned long long o = ((unsigned long long)sm[y] << 32) | (unsigned)~y;
        if (o > best) { best = o; bi = y; }
      }
    }
    lab[v] = (unsigned short)bi;
  }
  __syncthreads();
  for (int v = tid; v < NV; v += 256) {
    unsigned r = lab[v];
    while (1) { unsigned n = lab[r]; if (n == r) break; r = n; }
    lab[v] = (unsigned short)r;
    glab[v] = (unsigned short)r;
  }
  __syncthreads();
  unsigned my = 0;
  for (int v = tid; v < NV; v += 256) if (lab[v] == (unsigned short)v) ++my;
  cnt[tid] = my;
  __syncthreads();
  for (int off = 1; off < 256; off <<= 1) {
    unsigned t = (tid >= off) ? cnt[tid - off] : 0u;
    __syncthreads();
    cnt[tid] += t;
    __syncthreads();
  }
  unsigned base = cnt[tid] - my;
  for (int v = tid; v < NV; v += 256) {
    if (lab[v] == (unsigned short)v) {
      if (base < RCAP) {
        rootv[base] = (unsigned short)v;
        rord[base] = ((unsigned long long)sm[v] << 32) | (unsigned)~(unsigned)v;
      }
      ++base;
    }
  }
  if (tid == 255) rcnt[p] = (cnt[255] > RCAP) ? RCAP : cnt[255];
}

// ---------------------------------------------------------------------------
// Kernel 3: rank roots desc (elder order) -> dense ids + birth table
// ---------------------------------------------------------------------------
__global__ __launch_bounds__(256) void rank_root_k(float* ws) {
  __shared__ unsigned long long ro[RCAP];     // 24KB
  int p = blockIdx.x / 4, sl = blockIdx.x % 4, tid = threadIdx.x;
  const unsigned short* rootv = (const unsigned short*)((const char*)ws + OFF_ROOTV) + (size_t)p * RCAP;
  const unsigned long long* rord = (const unsigned long long*)((const char*)ws + OFF_RORD) + (size_t)p * RCAP;
  unsigned short* dense = (unsigned short*)((char*)ws + OFF_DENSE) + (size_t)p * NV;
  float* d2b = (float*)((char*)ws + OFF_D2B) + (size_t)p * RCAP;
  const unsigned* rcnt = (const unsigned*)((const char*)ws + OFF_RCNT);
  unsigned R = rcnt[p];
  for (unsigned i = tid; i < R; i += 256) ro[i] = rord[i];
  __syncthreads();
  unsigned RS = (R + 3) / 4;
  unsigned lo = sl * RS, hi = lo + RS; if (hi > R) hi = R;
  for (unsigned i = lo + tid; i < hi; i += 256) {
    unsigned long long oi = ro[i];
    unsigned r = 0;
    for (unsigned j = 0; j < R; ++j) r += (ro[j] > oi) ? 1u : 0u;
    dense[rootv[i]] = (unsigned short)r;
    d2b[r] = unmono((unsigned)(oi >> 32));
  }
}

// ---------------------------------------------------------------------------
// Kernel 4: boundary-edge hashing (dense pids, u32 events) + compaction
// ---------------------------------------------------------------------------
__global__ __launch_bounds__(256) void hash_k(float* ws) {
  __shared__ unsigned sm[NV];
  __shared__ unsigned hkey[HSZ];
  __shared__ unsigned hval[HSZ];
  __shared__ unsigned short dlab[NV];
  __shared__ unsigned cnt[256];
  int p = blockIdx.x, samp = p >> 1, neg = p & 1, tid = threadIdx.x;
  const float* res = (const float*)((const char*)ws + OFF_RES) + samp * NV;
  const unsigned short* glab = (const unsigned short*)((const char*)ws + OFF_LAB) + (size_t)p * NV;
  const unsigned short* gdense = (const unsigned short*)((const char*)ws + OFF_DENSE) + (size_t)p * NV;
  unsigned long long* gedges = (unsigned long long*)((char*)ws + OFF_EDGES) + (size_t)p * HSZ;
  unsigned* ecnt = (unsigned*)((char*)ws + OFF_ECNT);
  unsigned* lcnt = (unsigned*)((char*)ws + OFF_LCNT);
  float sgn = neg ? -1.f : 1.f;
  for (int i = tid; i < NV; i += 256) {
    sm[i] = mono32(sgn * res[i]);
    dlab[i] = gdense[glab[i]];
  }
  for (int s = tid; s < HSZ; s += 256) { hkey[s] = EMPTYK; hval[s] = 0u; }
  if (tid == 0) lcnt[p] = 0u;
  __syncthreads();
  for (int v = tid; v < NV; v += 256) {
    int r = v / GN, c = v - r * GN;
    unsigned a = dlab[v];
    unsigned sv = sm[v];
    bool vb[3] = { c < GN-1, r < GN-1, (!neg) && (r < GN-1) && (c < GN-1) };
    int  vo[3] = { 1, GN, GN+1 };
    #pragma unroll
    for (int d = 0; d < 3; ++d) {
      if (vb[d]) {
        unsigned w = (unsigned)(v + vo[d]);
        unsigned b = dlab[w];
        if (a != b) {
          unsigned sw = sm[w];
          unsigned ev = (sv < sw) ? sv : sw;
          unsigned dlo = (a < b) ? a : b, dhi = (a < b) ? b : a;
          unsigned pid = (dlo << 16) | dhi;
          unsigned h = (pid * 2654435761u) >> 19;
          for (int pr2 = 0; pr2 < HSZ; ++pr2) {
            unsigned k = hkey[h];
            if (k == EMPTYK) {
              unsigned old = atomicCAS(&hkey[h], EMPTYK, pid);
              k = (old == EMPTYK) ? pid : old;
            }
            if (k == pid) { atomicMax(&hval[h], ev); break; }
            h = (h + 1) & HMASK;
          }
        }
      }
    }
  }
  __syncthreads();
  unsigned my = 0;
  for (int s = tid; s < HSZ; s += 256) if (hkey[s] != EMPTYK) ++my;
  cnt[tid] = my;
  __syncthreads();
  for (int off = 1; off < 256; off <<= 1) {
    unsigned t = (tid >= off) ? cnt[tid - off] : 0u;
    __syncthreads();
    cnt[tid] += t;
    __syncthreads();
  }
  unsigned base = cnt[tid] - my;
  for (int s = tid; s < HSZ; s += 256) {
    if (hkey[s] != EMPTYK) {
      gedges[base++] = ((unsigned long long)hval[s] << 32) | hkey[s];
    }
  }
  if (tid == 255) ecnt[p] = cnt[255];
}

// ---------------------------------------------------------------------------
// Kernel 5: in-LDS LSD radix sort, DESCENDING by ev (bits 63:32), 8x4-bit
// passes, per-thread private counts (no atomics), stable. One block/problem.
// ---------------------------------------------------------------------------
__global__ __launch_bounds__(256) void sort_k(float* ws) {
  __shared__ unsigned long long bufA[HSZ];    // 64KB
  __shared__ unsigned long long bufB[HSZ];    // 64KB
  __shared__ unsigned cnt[16 * 256];          // 16KB
  __shared__ unsigned tot[16];
  int p = blockIdx.x, tid = threadIdx.x;
  unsigned long long* gedges = (unsigned long long*)((char*)ws + OFF_EDGES) + (size_t)p * HSZ;
  const unsigned* ecnt = (const unsigned*)((const char*)ws + OFF_ECNT);
  unsigned E = ecnt[p]; if (E > HSZ) E = HSZ;
  for (unsigned i = tid; i < E; i += 256) bufA[i] = gedges[i];
  __syncthreads();
  unsigned chunk = (E + 255) >> 8;
  unsigned lo = tid * chunk; if (lo > E) lo = E;
  unsigned hi = lo + chunk; if (hi > E) hi = E;
  unsigned long long* src = bufA;
  unsigned long long* dst = bufB;
  for (int pass = 0; pass < 8; ++pass) {
    int shift = 32 + pass * 4;
    for (int d = tid; d < 16 * 256; d += 256) cnt[d] = 0;
    __syncthreads();
    for (unsigned i = lo; i < hi; ++i) {
      unsigned slot = 15u - ((unsigned)(src[i] >> shift) & 15u);
      cnt[slot * 256 + tid] += 1u;
    }
    __syncthreads();
    if (tid < 16) {
      unsigned s = 0;
      for (int t = 0; t < 256; ++t) {
        unsigned c = cnt[tid * 256 + t];
        cnt[tid * 256 + t] = s;
        s += c;
      }
      tot[tid] = s;
    }
    __syncthreads();
    if (tid == 0) {
      unsigned s = 0;
      for (int d = 0; d < 16; ++d) { unsigned c = tot[d]; tot[d] = s; s += c; }
    }
    __syncthreads();
    for (unsigned i = lo; i < hi; ++i) {
      unsigned long long x = src[i];
      unsigned slot = 15u - ((unsigned)(x >> shift) & 15u);
      unsigned off = cnt[slot * 256 + tid];
      cnt[slot * 256 + tid] = off + 1u;
      dst[tot[slot] + off] = x;
    }
    __syncthreads();
    unsigned long long* t2 = src; src = dst; dst = t2;
  }
  for (unsigned i = tid; i < E; i += 256) gedges[i] = src[i];
}

// ---------------------------------------------------------------------------
// Kernel 6: prefix CC snapshots over the SORTED edge array. One block per
// problem; 4 epochs: snapshot compressed par, then union next 8 positional
// buckets (contiguous range). Snapshot s = CC of positions [0, s*8*cp).
// ---------------------------------------------------------------------------
__global__ __launch_bounds__(256) void prefix_cc_k(float* ws) {
  __shared__ unsigned par[RCAP];              // 12KB
  int p = blockIdx.x, tid = threadIdx.x;
  const unsigned long long* gedges = (const unsigned long long*)((const char*)ws + OFF_EDGES) + (size_t)p * HSZ;
  unsigned short* state = (unsigned short*)((char*)ws + OFF_STATE) + (size_t)p * SNAPN * RCAP;
  const unsigned* ecnt = (const unsigned*)((const char*)ws + OFF_ECNT);
  const unsigned* rcnt = (const unsigned*)((const char*)ws + OFF_RCNT);
  unsigned E = ecnt[p]; if (E > HSZ) E = HSZ;
  unsigned R = rcnt[p]; if (R > RCAP) R = RCAP;
  unsigned cp = (E + KB - 1) / KB;
  for (unsigned d = tid; d < R; d += 256) par[d] = d;
  __syncthreads();
  volatile unsigned* vpar = par;
  for (int s = 0; s < SNAPN; ++s) {
    for (unsigned d = tid; d < R; d += 256) {
      unsigned r = d;
      while (vpar[r] != r) r = vpar[r];
      par[d] = r;
      state[s * RCAP + d] = (unsigned short)r;
    }
    __syncthreads();
    unsigned e0 = (unsigned)s * 8u * cp; if (e0 > E) e0 = E;
    unsigned e1 = (unsigned)(s + 1) * 8u * cp; if (e1 > E) e1 = E;
    for (unsigned e = e0 + tid; e < e1; e += 256) {
      unsigned pid = (unsigned)gedges[e];
      uf_union(vpar, par, pid >> 16, pid & 0xffffu);
    }
    __syncthreads();
  }
}

// ---------------------------------------------------------------------------
// Kernel 7: bucketed elder-rule Kruskal over sorted edges. One block per
// (problem, bucket). Load snapshot bk>>3, replay residual prefix (contiguous,
// <=7*256 edges, CAS hooks), stage own (already sorted) segment, serial
// Kruskal on lane 0. Winner = min dense id (elder by construction).
// ---------------------------------------------------------------------------
__global__ __launch_bounds__(256) void kruskal_bucket_k(float* ws) {
  __shared__ unsigned par[RCAP];                // 12KB
  __shared__ float birth[RCAP];                 // 12KB
  __shared__ unsigned long long my[MYCAP + 1];  // 2KB
  int p = blockIdx.x / KB, bk = blockIdx.x % KB, tid = threadIdx.x;
  const unsigned long long* gedges = (const unsigned long long*)((const char*)ws + OFF_EDGES) + (size_t)p * HSZ;
  const float* d2b = (const float*)((const char*)ws + OFF_D2B) + (size_t)p * RCAP;
  const unsigned short* state = (const unsigned short*)((const char*)ws + OFF_STATE) + (size_t)p * SNAPN * RCAP + (size_t)(bk >> 3) * RCAP;
  const unsigned* ecnt = (const unsigned*)((const char*)ws + OFF_ECNT);
  const unsigned* rcnt = (const unsigned*)((const char*)ws + OFF_RCNT);
  unsigned* lcnt = (unsigned*)((char*)ws + OFF_LCNT);
  float* glist = (float*)((char*)ws + OFF_LIST) + (size_t)p * LISTCAP;
  unsigned E = ecnt[p]; if (E > HSZ) E = HSZ;
  unsigned R = rcnt[p]; if (R > RCAP) R = RCAP;
  unsigned cp = (E + KB - 1) / KB;
  unsigned rep_lo = (unsigned)(bk & ~7) * cp; if (rep_lo > E) rep_lo = E;
  unsigned own_lo = (unsigned)bk * cp;        if (own_lo > E) own_lo = E;
  unsigned own_hi = own_lo + cp;              if (own_hi > E) own_hi = E;
  for (unsigned d = tid; d < R; d += 256) { par[d] = state[d]; birth[d] = d2b[d]; }
  __syncthreads();
  volatile unsigned* vpar = par;
  // replay residual prefix [rep_lo, own_lo) — contiguous, coalesced
  for (unsigned e = rep_lo + tid; e < own_lo; e += 256) {
    unsigned pid = (unsigned)gedges[e];
    uf_union(vpar, par, pid >> 16, pid & 0xffffu);
  }
  // stage own segment (already in desc-ev order)
  for (unsigned e = own_lo + tid; e < own_hi; e += 256) my[e - own_lo] = gedges[e];
  __syncthreads();
  // compression sweep so serial finds are short
  for (unsigned d = tid; d < R; d += 256) {
    unsigned r = d;
    while (vpar[r] != r) r = vpar[r];
    par[d] = r;
  }
  __syncthreads();
  if (tid != 0) return;
  unsigned mc = own_hi - own_lo;
  my[mc] = 0ull;
  unsigned long long it = my[0];
  for (unsigned e = 0; e < mc; ++e) {
    unsigned long long nx = my[e + 1];
    unsigned ev = (unsigned)(it >> 32);
    unsigned pid = (unsigned)it;
    unsigned ca = pid >> 16, cb = pid & 0xffffu;
    while (1) {
      unsigned pa = par[ca], pb = par[cb];
      bool da = (pa == ca), db = (pb == cb);
      if (da && db) break;
      unsigned ga = par[pa], gb = par[pb];
      if (!da) { par[ca] = ga; ca = ga; }
      if (!db) { par[cb] = gb; cb = gb; }
    }
    if (ca != cb) {
      unsigned win = (ca < cb) ? ca : cb;
      unsigned los = (ca < cb) ? cb : ca;
      float bar = birth[los] - unmono(ev);
      unsigned idx = atomicAdd(&lcnt[p], 1u);
      if (idx < LISTCAP) glist[idx] = bar;
      par[los] = win;
    }
    it = nx;
  }
}

// ---------------------------------------------------------------------------
// Kernel 8: per-problem top-20 over compact bar list -> partial[p]
// ---------------------------------------------------------------------------
__global__ __launch_bounds__(256) void topk_k(float* ws) {
  __shared__ float sl[LISTCAP];
  __shared__ float rv[256];
  __shared__ int   ri[256];
  int p = blockIdx.x, tid = threadIdx.x;
  const float* glist = (const float*)((const char*)ws + OFF_LIST) + (size_t)p * LISTCAP;
  const unsigned* lcnt = (const unsigned*)((const char*)ws + OFF_LCNT);
  float* part = (float*)((char*)ws + OFF_PART);
  unsigned cnt = lcnt[p]; if (cnt > LISTCAP) cnt = LISTCAP;
  for (unsigned i = tid; i < cnt; i += 256) sl[i] = glist[i];
  __syncthreads();
  float acc = 0.f;
  for (int k = 0; k < K_TOP; ++k) {
    float mv = -1.f; int mi = LISTCAP;
    for (unsigned i = tid; i < cnt; i += 256) {
      float v = sl[i];
      if (v > mv) { mv = v; mi = (int)i; }
    }
    rv[tid] = mv; ri[tid] = mi;
    __syncthreads();
    for (int s = 128; s > 0; s >>= 1) {
      if (tid < s) {
        if (rv[tid+s] > rv[tid] || (rv[tid+s] == rv[tid] && ri[tid+s] < ri[tid])) {
          rv[tid] = rv[tid+s]; ri[tid] = ri[tid+s];
        }
      }
      __syncthreads();
    }
    if (tid == 0) {
      float best = rv[0] > 0.f ? rv[0] : 0.f;
      float sgnk = (k < 5) ? -1.f : 1.f;
      acc += sgnk * best * best;
      if (ri[0] < LISTCAP) sl[ri[0]] = -2.f;
    }
    __syncthreads();
  }
  if (tid == 0) part[p] = acc;
}

// ---------------------------------------------------------------------------
// Kernel 9: deterministic final reduction (mean over batch)
// ---------------------------------------------------------------------------
__global__ void final_k(float* ws, float* out) {
  if (threadIdx.x == 0 && blockIdx.x == 0) {
    const float* part = (const float*)((const char*)ws + OFF_PART);
    float s = 0.f;
    for (int i = 0; i < NPROB; ++i) s += part[i];
    out[0] = s / (float)NB;
  }
}

extern "C" void kernel_launch(void* const* d_in, const int* in_sizes, int n_in,
                              void* d_out, int out_size, void* d_ws, size_t ws_size,
                              hipStream_t stream) {
  const float* in = (const float*)d_in[0];
  float* ws = (float*)d_ws;
  float* out = (float*)d_out;
  hipLaunchKernelGGL(resize_k, dim3((NB * NV + 255) / 256), dim3(256), 0, stream, in, ws);
  hipLaunchKernelGGL(label_k, dim3(NPROB), dim3(256), 0, stream, ws);
  hipLaunchKernelGGL(rank_root_k, dim3(NPROB * 4), dim3(256), 0, stream, ws);
  hipLaunchKernelGGL(hash_k, dim3(NPROB), dim3(256), 0, stream, ws);
  hipLaunchKernelGGL(sort_k, dim3(NPROB), dim3(256), 0, stream, ws);
  hipLaunchKernelGGL(prefix_cc_k, dim3(NPROB), dim3(256), 0, stream, ws);
  hipLaunchKernelGGL(kruskal_bucket_k, dim3(NPROB * KB), dim3(256), 0, stream, ws);
  hipLaunchKernelGGL(topk_k, dim3(NPROB), dim3(256), 0, stream, ws);
  hipLaunchKernelGGL(final_k, dim3(1), dim3(64), 0, stream, ws, out);
}

// Round 11
// 475.344 us; speedup vs baseline: 2.5438x; 1.5966x over previous
//
#include <hip/hip_runtime.h>
#include <math.h>

#define NB 16
#define INW 256
#define GN 100
#define NV (GN*GN)          // 10000
#define NPROB (NB*2)        // 32
#define K_TOP 20
#define HSZ 8192
#define EMPTYK 0xFFFFFFFFu
#define KB 64               // positional buckets per problem
#define SNAPN 8             // snapshots (every 8 buckets)
#define RCAP 3072           // max regions per problem
#define MYCAP 128           // max edges per bucket (= ceil(HSZ/KB))
#define LISTCAP 3072        // max bars per problem

// ws layout (end ~5.0 MB)
#define OFF_RES   0               // NB*NV f32 = 640000   (dead after hash_k)
#define OFF_LAB   640000          // NPROB*NV u16         (dead after hash_k)
#define OFF_DENSE 1280000         // NPROB*NV u16         (dead after hash_k)
#define OFF_STATE 0               // overlay: NPROB*SNAPN*RCAP u16 = 1572864 (<1920000)
#define OFF_ROOTV 1920000         // NPROB*RCAP u16 = 196608
#define OFF_D2B   2116608         // NPROB*RCAP f32 = 393216
#define OFF_EDGES 2509824         // NPROB*HSZ u64 = 2097152
#define OFF_RORD  OFF_EDGES       // overlay: rord dead before hash_k writes edges
#define OFF_ECNT  4606976         // NPROB u32
#define OFF_RCNT  4607104         // NPROB u32
#define OFF_LCNT  4607232         // NPROB u32
#define OFF_LIST  4607360         // NPROB*LISTCAP f32 = 393216
#define OFF_PART  5000576         // NPROB f32

__device__ __forceinline__ int imin(int a, int b){ return a < b ? a : b; }
__device__ __forceinline__ int imax(int a, int b){ return a > b ? a : b; }

__device__ __forceinline__ unsigned mono32(float f){
  unsigned b = __float_as_uint(f);
  return (b & 0x80000000u) ? ~b : (b | 0x80000000u);
}
__device__ __forceinline__ float unmono(unsigned m){
  unsigned b = (m & 0x80000000u) ? (m ^ 0x80000000u) : ~m;
  return __uint_as_float(b);
}

__device__ __forceinline__ unsigned uf_find(volatile unsigned* par, unsigned x){
  unsigned p = par[x];
  while (p != x) {
    unsigned g = par[p];
    if (g != p) par[x] = g;
    x = g;
    p = par[x];
  }
  return x;
}
__device__ __forceinline__ void uf_union(volatile unsigned* vpar, unsigned* par,
                                         unsigned a, unsigned b){
  while (1) {
    unsigned ra = uf_find(vpar, a);
    unsigned rb = uf_find(vpar, b);
    if (ra == rb) break;
    unsigned lo = (ra < rb) ? ra : rb, hi = (ra < rb) ? rb : ra;
    if (atomicCAS(&par[hi], hi, lo) == hi) break;
    a = lo; b = hi;
  }
}

__device__ __forceinline__ void cub_w(int i, int& j0, float w[4]) {
  double inv = (double)INW / (double)GN;
  double sf  = ((double)i + 0.5) * inv - 0.5;
  j0 = (int)floor(sf) - 1;
  double wd[4]; double s = 0.0;
  #pragma unroll
  for (int k = 0; k < 4; ++k) {
    int j = j0 + k;
    double t = fabs(sf - (double)j);
    double v;
    if (t < 1.0)      v = ((1.5*t - 2.5)*t)*t + 1.0;
    else if (t < 2.0) v = ((-0.5*t + 2.5)*t - 4.0)*t + 2.0;
    else              v = 0.0;
    if (j < 0 || j >= INW) v = 0.0;
    wd[k] = v; s += v;
  }
  #pragma unroll
  for (int k = 0; k < 4; ++k) w[k] = (float)(wd[k] / s);
}

// ---------------------------------------------------------------------------
// Kernel 1: separable bicubic resize 256x256 -> 100x100
// ---------------------------------------------------------------------------
__global__ __launch_bounds__(256) void resize_k(const float* __restrict__ in, float* ws) {
  float* outp = (float*)((char*)ws + OFF_RES);
  int idx = blockIdx.x * 256 + threadIdx.x;
  if (idx >= NB * NV) return;
  int b = idx / NV; int rem = idx - b * NV;
  int i = rem / GN; int j = rem - i * GN;
  const float* img = in + (size_t)b * INW * INW;
  int r0, c0; float wr[4], wc[4];
  cub_w(i, r0, wr);
  cub_w(j, c0, wc);
  float acc = 0.f;
  #pragma unroll
  for (int kr = 0; kr < 4; ++kr) {
    int rr = imin(imax(r0 + kr, 0), INW - 1);
    const float* row = img + rr * INW;
    int c0c = imin(imax(c0 + 0, 0), INW - 1);
    int c1c = imin(imax(c0 + 1, 0), INW - 1);
    int c2c = imin(imax(c0 + 2, 0), INW - 1);
    int c3c = imin(imax(c0 + 3, 0), INW - 1);
    float rs = wc[0]*row[c0c] + wc[1]*row[c1c] + wc[2]*row[c2c] + wc[3]*row[c3c];
    acc += wr[kr] * rs;
  }
  outp[idx] = acc;
}

// ---------------------------------------------------------------------------
// Kernel 2: watershed labels + root compaction
// ---------------------------------------------------------------------------
__global__ __launch_bounds__(256) void label_k(float* ws) {
  __shared__ unsigned sm[NV];
  __shared__ unsigned short lab[NV];
  __shared__ unsigned cnt[256];
  int p = blockIdx.x, samp = p >> 1, neg = p & 1, tid = threadIdx.x;
  const float* res = (const float*)((const char*)ws + OFF_RES) + samp * NV;
  unsigned short* glab = (unsigned short*)((char*)ws + OFF_LAB) + (size_t)p * NV;
  unsigned short* rootv = (unsigned short*)((char*)ws + OFF_ROOTV) + (size_t)p * RCAP;
  unsigned long long* rord = (unsigned long long*)((char*)ws + OFF_RORD) + (size_t)p * RCAP;
  unsigned* rcnt = (unsigned*)((char*)ws + OFF_RCNT);
  float sgn = neg ? -1.f : 1.f;
  for (int i = tid; i < NV; i += 256) sm[i] = mono32(sgn * res[i]);
  __syncthreads();
  const int nd = neg ? 4 : 6;
  for (int v = tid; v < NV; v += 256) {
    int r = v / GN, c = v - r * GN;
    unsigned long long best = ((unsigned long long)sm[v] << 32) | (unsigned)~(unsigned)v;
    unsigned bi = (unsigned)v;
    bool cb[6] = { c < GN-1, c > 0, r < GN-1, r > 0,
                   (r < GN-1) && (c < GN-1), (r > 0) && (c > 0) };
    int  off[6] = { 1, -1, GN, -GN, GN+1, -(GN+1) };
    #pragma unroll
    for (int d = 0; d < 6; ++d) {
      if (d < nd && cb[d]) {
        unsigned y = (unsigned)(v + off[d]);
        unsigned long long o = ((unsigned long long)sm[y] << 32) | (unsigned)~y;
        if (o > best) { best = o; bi = y; }
      }
    }
    lab[v] = (unsigned short)bi;
  }
  __syncthreads();
  for (int v = tid; v < NV; v += 256) {
    unsigned r = lab[v];
    while (1) { unsigned n = lab[r]; if (n == r) break; r = n; }
    lab[v] = (unsigned short)r;
    glab[v] = (unsigned short)r;
  }
  __syncthreads();
  unsigned my = 0;
  for (int v = tid; v < NV; v += 256) if (lab[v] == (unsigned short)v) ++my;
  cnt[tid] = my;
  __syncthreads();
  for (int off = 1; off < 256; off <<= 1) {
    unsigned t = (tid >= off) ? cnt[tid - off] : 0u;
    __syncthreads();
    cnt[tid] += t;
    __syncthreads();
  }
  unsigned base = cnt[tid] - my;
  for (int v = tid; v < NV; v += 256) {
    if (lab[v] == (unsigned short)v) {
      if (base < RCAP) {
        rootv[base] = (unsigned short)v;
        rord[base] = ((unsigned long long)sm[v] << 32) | (unsigned)~(unsigned)v;
      }
      ++base;
    }
  }
  if (tid == 255) rcnt[p] = (cnt[255] > RCAP) ? RCAP : cnt[255];
}

// ---------------------------------------------------------------------------
// Kernel 3: rank roots desc (elder order) -> dense ids + birth table
// ---------------------------------------------------------------------------
__global__ __launch_bounds__(256) void rank_root_k(float* ws) {
  __shared__ unsigned long long ro[RCAP];
  int p = blockIdx.x / 4, sl = blockIdx.x % 4, tid = threadIdx.x;
  const unsigned short* rootv = (const unsigned short*)((const char*)ws + OFF_ROOTV) + (size_t)p * RCAP;
  const unsigned long long* rord = (const unsigned long long*)((const char*)ws + OFF_RORD) + (size_t)p * RCAP;
  unsigned short* dense = (unsigned short*)((char*)ws + OFF_DENSE) + (size_t)p * NV;
  float* d2b = (float*)((char*)ws + OFF_D2B) + (size_t)p * RCAP;
  const unsigned* rcnt = (const unsigned*)((const char*)ws + OFF_RCNT);
  unsigned R = rcnt[p];
  for (unsigned i = tid; i < R; i += 256) ro[i] = rord[i];
  __syncthreads();
  unsigned RS = (R + 3) / 4;
  unsigned lo = sl * RS, hi = lo + RS; if (hi > R) hi = R;
  for (unsigned i = lo + tid; i < hi; i += 256) {
    unsigned long long oi = ro[i];
    unsigned r = 0;
    for (unsigned j = 0; j < R; ++j) r += (ro[j] > oi) ? 1u : 0u;
    dense[rootv[i]] = (unsigned short)r;
    d2b[r] = unmono((unsigned)(oi >> 32));
  }
}

// ---------------------------------------------------------------------------
// Kernel 4: boundary-edge hashing (dense pids, u32 events) + compaction
// ---------------------------------------------------------------------------
__global__ __launch_bounds__(256) void hash_k(float* ws) {
  __shared__ unsigned sm[NV];
  __shared__ unsigned hkey[HSZ];
  __shared__ unsigned hval[HSZ];
  __shared__ unsigned short dlab[NV];
  __shared__ unsigned cnt[256];
  int p = blockIdx.x, samp = p >> 1, neg = p & 1, tid = threadIdx.x;
  const float* res = (const float*)((const char*)ws + OFF_RES) + samp * NV;
  const unsigned short* glab = (const unsigned short*)((const char*)ws + OFF_LAB) + (size_t)p * NV;
  const unsigned short* gdense = (const unsigned short*)((const char*)ws + OFF_DENSE) + (size_t)p * NV;
  unsigned long long* gedges = (unsigned long long*)((char*)ws + OFF_EDGES) + (size_t)p * HSZ;
  unsigned* ecnt = (unsigned*)((char*)ws + OFF_ECNT);
  unsigned* lcnt = (unsigned*)((char*)ws + OFF_LCNT);
  float sgn = neg ? -1.f : 1.f;
  for (int i = tid; i < NV; i += 256) {
    sm[i] = mono32(sgn * res[i]);
    dlab[i] = gdense[glab[i]];
  }
  for (int s = tid; s < HSZ; s += 256) { hkey[s] = EMPTYK; hval[s] = 0u; }
  if (tid == 0) lcnt[p] = 0u;
  __syncthreads();
  for (int v = tid; v < NV; v += 256) {
    int r = v / GN, c = v - r * GN;
    unsigned a = dlab[v];
    unsigned sv = sm[v];
    bool vb[3] = { c < GN-1, r < GN-1, (!neg) && (r < GN-1) && (c < GN-1) };
    int  vo[3] = { 1, GN, GN+1 };
    #pragma unroll
    for (int d = 0; d < 3; ++d) {
      if (vb[d]) {
        unsigned w = (unsigned)(v + vo[d]);
        unsigned b = dlab[w];
        if (a != b) {
          unsigned sw = sm[w];
          unsigned ev = (sv < sw) ? sv : sw;
          unsigned dlo = (a < b) ? a : b, dhi = (a < b) ? b : a;
          unsigned pid = (dlo << 16) | dhi;
          unsigned h = (pid * 2654435761u) >> 19;
          for (int pr2 = 0; pr2 < HSZ; ++pr2) {
            unsigned k = hkey[h];
            if (k == EMPTYK) {
              unsigned old = atomicCAS(&hkey[h], EMPTYK, pid);
              k = (old == EMPTYK) ? pid : old;
            }
            if (k == pid) { atomicMax(&hval[h], ev); break; }
            h = (h + 1) & (HSZ - 1);
          }
        }
      }
    }
  }
  __syncthreads();
  unsigned my = 0;
  for (int s = tid; s < HSZ; s += 256) if (hkey[s] != EMPTYK) ++my;
  cnt[tid] = my;
  __syncthreads();
  for (int off = 1; off < 256; off <<= 1) {
    unsigned t = (tid >= off) ? cnt[tid - off] : 0u;
    __syncthreads();
    cnt[tid] += t;
    __syncthreads();
  }
  unsigned base = cnt[tid] - my;
  for (int s = tid; s < HSZ; s += 256) {
    if (hkey[s] != EMPTYK) {
      gedges[base++] = ((unsigned long long)hval[s] << 32) | hkey[s];
    }
  }
  if (tid == 255) ecnt[p] = cnt[255];
}

// ---------------------------------------------------------------------------
// Kernel 5: FUSED in-LDS radix sort (desc by ev) + prefix-CC snapshots.
// One block/problem. After sort, edges live in LDS; CC unions read LDS,
// snapshots of compressed par go to global STATE.
// ---------------------------------------------------------------------------
__global__ __launch_bounds__(256) void sortcc_k(float* ws) {
  __shared__ unsigned long long bufA[HSZ];    // 64KB
  __shared__ unsigned long long bufB[HSZ];    // 64KB (reused as par after sort)
  __shared__ unsigned cnt[16 * 256];          // 16KB
  __shared__ unsigned tot[16];
  int p = blockIdx.x, tid = threadIdx.x;
  unsigned long long* gedges = (unsigned long long*)((char*)ws + OFF_EDGES) + (size_t)p * HSZ;
  unsigned short* state = (unsigned short*)((char*)ws + OFF_STATE) + (size_t)p * SNAPN * RCAP;
  const unsigned* ecnt = (const unsigned*)((const char*)ws + OFF_ECNT);
  const unsigned* rcnt = (const unsigned*)((const char*)ws + OFF_RCNT);
  unsigned E = ecnt[p]; if (E > HSZ) E = HSZ;
  unsigned R = rcnt[p]; if (R > RCAP) R = RCAP;
  for (unsigned i = tid; i < E; i += 256) bufA[i] = gedges[i];
  __syncthreads();
  unsigned chunk = (E + 255) >> 8;
  unsigned lo = tid * chunk; if (lo > E) lo = E;
  unsigned hi = lo + chunk; if (hi > E) hi = E;
  unsigned long long* src = bufA;
  unsigned long long* dst = bufB;
  for (int pass = 0; pass < 8; ++pass) {
    int shift = 32 + pass * 4;
    for (int d = tid; d < 16 * 256; d += 256) cnt[d] = 0;
    __syncthreads();
    for (unsigned i = lo; i < hi; ++i) {
      unsigned slot = 15u - ((unsigned)(src[i] >> shift) & 15u);
      cnt[slot * 256 + tid] += 1u;
    }
    __syncthreads();
    if (tid < 16) {
      unsigned s = 0;
      for (int t = 0; t < 256; ++t) {
        unsigned c = cnt[tid * 256 + t];
        cnt[tid * 256 + t] = s;
        s += c;
      }
      tot[tid] = s;
    }
    __syncthreads();
    if (tid == 0) {
      unsigned s = 0;
      for (int d = 0; d < 16; ++d) { unsigned c = tot[d]; tot[d] = s; s += c; }
    }
    __syncthreads();
    for (unsigned i = lo; i < hi; ++i) {
      unsigned long long x = src[i];
      unsigned slot = 15u - ((unsigned)(x >> shift) & 15u);
      unsigned off = cnt[slot * 256 + tid];
      cnt[slot * 256 + tid] = off + 1u;
      dst[tot[slot] + off] = x;
    }
    __syncthreads();
    unsigned long long* t2 = src; src = dst; dst = t2;
  }
  // 8 passes -> src == bufA. Write back sorted edges; bufB becomes par.
  for (unsigned i = tid; i < E; i += 256) gedges[i] = bufA[i];
  unsigned* par = (unsigned*)bufB;
  for (unsigned d = tid; d < R; d += 256) par[d] = d;
  __syncthreads();
  volatile unsigned* vpar = par;
  unsigned cp = (E + KB - 1) / KB;
  for (int s = 0; s < SNAPN; ++s) {
    for (unsigned d = tid; d < R; d += 256) {
      unsigned r = d;
      while (vpar[r] != r) r = vpar[r];
      par[d] = r;
      state[s * RCAP + d] = (unsigned short)r;
    }
    __syncthreads();
    unsigned e0 = (unsigned)s * 8u * cp; if (e0 > E) e0 = E;
    unsigned e1 = (unsigned)(s + 1) * 8u * cp; if (e1 > E) e1 = E;
    for (unsigned e = e0 + tid; e < e1; e += 256) {
      unsigned pid = (unsigned)bufA[e];
      uf_union(vpar, par, pid >> 16, pid & 0xffffu);
    }
    __syncthreads();
  }
}

// ---------------------------------------------------------------------------
// Kernel 6: bucketed Kruskal with speculative root hints.
// Load snapshot bk>>3, replay residual contiguous prefix, compress, then a
// parallel hint phase (par compressed -> root = 1 read; speculative loser
// birth from d2b). Serial lane-0 loop skips intra-edges free, verifies hints,
// stages bars in LDS; one atomicAdd + parallel flush at the end.
// ---------------------------------------------------------------------------
__global__ __launch_bounds__(256) void kruskal_bucket_k(float* ws) {
  __shared__ unsigned par[RCAP];                // 12KB
  __shared__ unsigned hintR[MYCAP];             // (ra<<16)|rb
  __shared__ unsigned hintE[MYCAP];             // ev
  __shared__ float    hintB[MYCAP];             // speculative loser birth
  __shared__ float    barbuf[MYCAP];
  __shared__ unsigned nb_sh, base_sh;
  int p = blockIdx.x / KB, bk = blockIdx.x % KB, tid = threadIdx.x;
  const unsigned long long* gedges = (const unsigned long long*)((const char*)ws + OFF_EDGES) + (size_t)p * HSZ;
  const float* d2b = (const float*)((const char*)ws + OFF_D2B) + (size_t)p * RCAP;
  const unsigned short* state = (const unsigned short*)((const char*)ws + OFF_STATE) + (size_t)p * SNAPN * RCAP + (size_t)(bk >> 3) * RCAP;
  const unsigned* ecnt = (const unsigned*)((const char*)ws + OFF_ECNT);
  const unsigned* rcnt = (const unsigned*)((const char*)ws + OFF_RCNT);
  unsigned* lcnt = (unsigned*)((char*)ws + OFF_LCNT);
  float* glist = (float*)((char*)ws + OFF_LIST) + (size_t)p * LISTCAP;
  unsigned E = ecnt[p]; if (E > HSZ) E = HSZ;
  unsigned R = rcnt[p]; if (R > RCAP) R = RCAP;
  unsigned cp = (E + KB - 1) / KB;
  unsigned rep_lo = (unsigned)(bk & ~7) * cp; if (rep_lo > E) rep_lo = E;
  unsigned own_lo = (unsigned)bk * cp;        if (own_lo > E) own_lo = E;
  unsigned own_hi = own_lo + cp;              if (own_hi > E) own_hi = E;
  unsigned mc = own_hi - own_lo;
  for (unsigned d = tid; d < R; d += 256) par[d] = state[d];
  __syncthreads();
  volatile unsigned* vpar = par;
  for (unsigned e = rep_lo + tid; e < own_lo; e += 256) {
    unsigned pid = (unsigned)gedges[e];
    uf_union(vpar, par, pid >> 16, pid & 0xffffu);
  }
  __syncthreads();
  // full compression: after this, par[x] is the root for every x
  for (unsigned d = tid; d < R; d += 256) {
    unsigned r = d;
    while (vpar[r] != r) r = vpar[r];
    par[d] = r;
  }
  __syncthreads();
  // hint phase: one edge per thread
  if (tid < mc) {
    unsigned long long it = gedges[own_lo + tid];
    unsigned pid = (unsigned)it;
    unsigned ra = par[pid >> 16];
    unsigned rb = par[pid & 0xffffu];
    hintR[tid] = (ra << 16) | rb;
    hintE[tid] = (unsigned)(it >> 32);
    hintB[tid] = d2b[(ra > rb) ? ra : rb];
  }
  __syncthreads();
  if (tid >= 64) return;
  const int lane = tid;
  if (lane == 0) {
    unsigned nb = 0;
    for (unsigned e = 0; e < mc; ++e) {
      unsigned h = hintR[e];
      unsigned ra = h >> 16, rb = h & 0xffffu;
      if (ra == rb) continue;                  // intra at bucket start: free skip
      // follow chains (short: only within-bucket merges added depth)
      unsigned ca = ra, pa = par[ca];
      while (pa != ca) { unsigned ga = par[pa]; par[ca] = ga; ca = ga; pa = par[ca]; }
      unsigned cb = rb, pb = par[cb];
      while (pb != cb) { unsigned gb = par[pb]; par[cb] = gb; cb = gb; pb = par[cb]; }
      if (ca == cb) continue;
      unsigned win = (ca < cb) ? ca : cb;
      unsigned los = (ca < cb) ? cb : ca;
      float birth = (ca == ra && cb == rb) ? hintB[e] : d2b[los];
      barbuf[nb++] = birth - unmono(hintE[e]);
      par[los] = win;
    }
    nb_sh = nb;
  }
  __asm__ volatile("s_waitcnt lgkmcnt(0)" ::: "memory");
  __builtin_amdgcn_wave_barrier();
  if (lane == 0) base_sh = atomicAdd(&lcnt[p], nb_sh);
  __asm__ volatile("s_waitcnt vmcnt(0) lgkmcnt(0)" ::: "memory");
  __builtin_amdgcn_wave_barrier();
  unsigned nb = nb_sh, base = base_sh;
  for (unsigned i = lane; i < nb; i += 64) {
    unsigned idx = base + i;
    if (idx < LISTCAP) glist[idx] = barbuf[i];
  }
}

// ---------------------------------------------------------------------------
// Kernel 7: per-problem top-20 over compact bar list -> partial[p]
// ---------------------------------------------------------------------------
__global__ __launch_bounds__(256) void topk_k(float* ws) {
  __shared__ float sl[LISTCAP];
  __shared__ float rv[256];
  __shared__ int   ri[256];
  int p = blockIdx.x, tid = threadIdx.x;
  const float* glist = (const float*)((const char*)ws + OFF_LIST) + (size_t)p * LISTCAP;
  const unsigned* lcnt = (const unsigned*)((const char*)ws + OFF_LCNT);
  float* part = (float*)((char*)ws + OFF_PART);
  unsigned cnt = lcnt[p]; if (cnt > LISTCAP) cnt = LISTCAP;
  for (unsigned i = tid; i < cnt; i += 256) sl[i] = glist[i];
  __syncthreads();
  float acc = 0.f;
  for (int k = 0; k < K_TOP; ++k) {
    float mv = -1.f; int mi = LISTCAP;
    for (unsigned i = tid; i < cnt; i += 256) {
      float v = sl[i];
      if (v > mv) { mv = v; mi = (int)i; }
    }
    rv[tid] = mv; ri[tid] = mi;
    __syncthreads();
    for (int s = 128; s > 0; s >>= 1) {
      if (tid < s) {
        if (rv[tid+s] > rv[tid] || (rv[tid+s] == rv[tid] && ri[tid+s] < ri[tid])) {
          rv[tid] = rv[tid+s]; ri[tid] = ri[tid+s];
        }
      }
      __syncthreads();
    }
    if (tid == 0) {
      float best = rv[0] > 0.f ? rv[0] : 0.f;
      float sgnk = (k < 5) ? -1.f : 1.f;
      acc += sgnk * best * best;
      if (ri[0] < LISTCAP) sl[ri[0]] = -2.f;
    }
    __syncthreads();
  }
  if (tid == 0) part[p] = acc;
}

// ---------------------------------------------------------------------------
// Kernel 8: deterministic final reduction (mean over batch)
// ---------------------------------------------------------------------------
__global__ void final_k(float* ws, float* out) {
  if (threadIdx.x == 0 && blockIdx.x == 0) {
    const float* part = (const float*)((const char*)ws + OFF_PART);
    float s = 0.f;
    for (int i = 0; i < NPROB; ++i) s += part[i];
    out[0] = s / (float)NB;
  }
}

extern "C" void kernel_launch(void* const* d_in, const int* in_sizes, int n_in,
                              void* d_out, int out_size, void* d_ws, size_t ws_size,
                              hipStream_t stream) {
  const float* in = (const float*)d_in[0];
  float* ws = (float*)d_ws;
  float* out = (float*)d_out;
  hipLaunchKernelGGL(resize_k, dim3((NB * NV + 255) / 256), dim3(256), 0, stream, in, ws);
  hipLaunchKernelGGL(label_k, dim3(NPROB), dim3(256), 0, stream, ws);
  hipLaunchKernelGGL(rank_root_k, dim3(NPROB * 4), dim3(256), 0, stream, ws);
  hipLaunchKernelGGL(hash_k, dim3(NPROB), dim3(256), 0, stream, ws);
  hipLaunchKernelGGL(sortcc_k, dim3(NPROB), dim3(256), 0, stream, ws);
  hipLaunchKernelGGL(kruskal_bucket_k, dim3(NPROB * KB), dim3(256), 0, stream, ws);
  hipLaunchKernelGGL(topk_k, dim3(NPROB), dim3(256), 0, stream, ws);
  hipLaunchKernelGGL(final_k, dim3(1), dim3(64), 0, stream, ws, out);
}